// Round 11
// baseline (85.587 us; speedup 1.0000x reference)
//
#include <hip/hip_runtime.h>
#include <hip/hip_bf16.h>

// B=128, LQ=32, LD=256, HID=768, DIM=128
typedef __attribute__((ext_vector_type(8))) short short8;
typedef __attribute__((ext_vector_type(4))) float f32x4;
typedef __attribute__((ext_vector_type(16))) float f32x16;

#define MFMA16(a, b, c) __builtin_amdgcn_mfma_f32_16x16x32_bf16(a, b, c, 0, 0, 0)
#define MFMA32(a, b, c) __builtin_amdgcn_mfma_f32_32x32x16_bf16(a, b, c, 0, 0, 0)

__device__ __forceinline__ short f2bf(float f) {
    union { float f; unsigned u; } x; x.f = f;
    unsigned r = x.u + 0x7fffu + ((x.u >> 16) & 1u);  // RNE
    return (short)(r >> 16);
}

__device__ __forceinline__ short8 cvt8(const float4& a, const float4& b) {
    short8 v;
    v[0]=f2bf(a.x); v[1]=f2bf(a.y); v[2]=f2bf(a.z); v[3]=f2bf(a.w);
    v[4]=f2bf(b.x); v[5]=f2bf(b.y); v[6]=f2bf(b.z); v[7]=f2bf(b.w);
    return v;
}

// ---------------------------------------------------------------------------
// Kernel A: pure streaming cvt. Xbf[row][768] bf16 <- concat(qh, dh) fp32.
// Copy-kernel shape: grid-stride, no barriers, no consumers -> copy-class BW.
// chunk c (8 elems): fp32 flat = c*8 (row-major concat since 768 | boundary).
// ---------------------------------------------------------------------------
__global__ __launch_bounds__(256) void cvt_kernel(
    const float* __restrict__ qh, const float* __restrict__ dh,
    unsigned short* __restrict__ Xbf)
{
    const int gtid = blockIdx.x * 256 + threadIdx.x;   // 0..442367
    #pragma unroll
    for (int i = 0; i < 8; ++i) {
        const int c = gtid + i * 442368;               // 8 chunks/thread, coalesced
        const size_t f = (size_t)c * 8;
        const float* src = (f < 3145728) ? (qh + f) : (dh + (f - 3145728));
        float4 a = reinterpret_cast<const float4*>(src)[0];
        float4 b = reinterpret_cast<const float4*>(src)[1];
        *reinterpret_cast<short8*>(Xbf + f) = cvt8(a, b);
    }
}

// ---------------------------------------------------------------------------
// Kernel 0: W [128x768] fp32 -> bf16 B-fragment image for 16x16x32 MFMA.
// Slot gt = (kc*16 + f)*64 + lane, f = ks*8 + dimt:
//   dim = (f&7)*16 + (lane&15), k = kc*64 + (f>>3)*32 + (lane>>4)*8 + j.
// Per-K-chunk image is a LINEAR 16 KB block -> global_load_lds staging.
// ---------------------------------------------------------------------------
__global__ __launch_bounds__(256) void wprep_kernel(
    const float* __restrict__ W, unsigned short* __restrict__ Wimg)
{
    const int gt = blockIdx.x * 256 + threadIdx.x;    // 0..12287
    const int kc = gt >> 10, rem = gt & 1023;
    const int f = rem >> 6, lane = rem & 63;
    const int dim = (f & 7) * 16 + (lane & 15);
    const int kb  = kc * 64 + (f >> 3) * 32 + (lane >> 4) * 8;
    const float4* s = reinterpret_cast<const float4*>(W + dim * 768 + kb);
    float4 a = s[0], b = s[1];
    *reinterpret_cast<short8*>(Wimg + (size_t)gt * 8) = cvt8(a, b);
}

// ---------------------------------------------------------------------------
// Kernel 1: P[row][dim] = l2norm(Xbf[row] @ W^T), bf16 out. ALL-bf16 GEMM.
// BM=64, BK=64, 4 waves (wave = 32 rows x 64 dims, 2x4 16x16 frags).
// BOTH operands via global_load_lds (X: per-lane src w/ pre-swizzled chunks,
// T21; W: linear frag image). No VALU cvt, no reg staging -> nothing stalls
// except the 6 DMA loads, which get the whole compute phase to land.
// ---------------------------------------------------------------------------
__global__ __launch_bounds__(256) void proj_norm_kernel(
    const unsigned short* __restrict__ Xbf, const unsigned short* __restrict__ Wimg,
    const int* __restrict__ dmask,
    unsigned short* __restrict__ Qb, unsigned short* __restrict__ Db)
{
    __shared__ __align__(16) short Xl[2][4096];     // [64 rows][64 k] flat, swz, 8 KB
    __shared__ __align__(16) short Wl[2][8192];     // frag image, linear, 16 KB
    __shared__ float ssb[4][32];

    const int tid = threadIdx.x;
    const int wave = tid >> 6, lane = tid & 63;
    const int l = lane & 15, g = lane >> 4;
    const int rw = (wave & 1) * 32;                 // wave's row base
    const int dn4 = (wave >> 1) * 4;                // wave's dim-tile base
    const int dn = dn4 * 16;

    const int rowbase = blockIdx.x * 64;            // into combined Xbf
    const bool isQ = rowbase < 4096;
    const int prow = isQ ? rowbase : rowbase - 4096;

    auto xstage = [&](int t, int p) {               // 2 gld_lds/wave
        #pragma unroll
        for (int i = 0; i < 2; ++i) {
            const int c8 = i * 256 + tid;           // 16B-chunk id: row=c8>>3, cl=c8&7
            const int row = c8 >> 3, cl = c8 & 7;
            const unsigned short* src =
                Xbf + (size_t)(rowbase + row) * 768 + t * 64 + ((cl ^ (row & 7)) * 8);
            __builtin_amdgcn_global_load_lds(
                (const __attribute__((address_space(1))) void*)src,
                (__attribute__((address_space(3))) void*)(&Xl[p][i * 2048 + wave * 512]),
                16, 0, 0);
        }
    };
    auto wstage = [&](int t, int p) {               // 4 gld_lds/wave
        const unsigned short* src = Wimg + (size_t)t * 8192 + wave * 2048 + lane * 8;
        #pragma unroll
        for (int i = 0; i < 4; ++i)
            __builtin_amdgcn_global_load_lds(
                (const __attribute__((address_space(1))) void*)(src + i * 512),
                (__attribute__((address_space(3))) void*)(&Wl[p][wave * 2048 + i * 512]),
                16, 0, 0);
    };

    f32x4 acc[2][4];
    #pragma unroll
    for (int rt = 0; rt < 2; ++rt)
        #pragma unroll
        for (int n = 0; n < 4; ++n) acc[rt][n] = (f32x4)(0.0f);

    auto compute = [&](int p) {
        #pragma unroll
        for (int ks = 0; ks < 2; ++ks) {
            short8 af[2];
            #pragma unroll
            for (int rt = 0; rt < 2; ++rt) {
                const int row = rw + rt * 16 + l;
                const int c = (ks * 4 + g) ^ (row & 7);       // swizzled read (T21)
                af[rt] = *reinterpret_cast<const short8*>(&Xl[p][row * 64 + c * 8]);
            }
            #pragma unroll
            for (int n = 0; n < 4; ++n) {
                short8 bf = *reinterpret_cast<const short8*>(
                    &Wl[p][(ks * 8 + dn4 + n) * 512 + lane * 8]);
                acc[0][n] = MFMA16(af[0], bf, acc[0][n]);
                acc[1][n] = MFMA16(af[1], bf, acc[1][n]);
            }
        }
    };

    // prologue
    xstage(0, 0); wstage(0, 0);
    __syncthreads();

    for (int t = 0; t < 12; ++t) {
        const int p = t & 1;
        if (t < 11) { xstage(t + 1, p ^ 1); wstage(t + 1, p ^ 1); }  // issue early
        compute(p);
        __syncthreads();   // drains the 6 DMA loads (had full compute to fly)
    }

    // --- L2 norm: acc[rt][n][r] = C[row=rw+rt*16+g*4+r][dim=dn+n*16+l] ---
    #pragma unroll
    for (int rt = 0; rt < 2; ++rt)
        #pragma unroll
        for (int r = 0; r < 4; ++r) {
            float s = 0.f;
            #pragma unroll
            for (int n = 0; n < 4; ++n) s += acc[rt][n][r] * acc[rt][n][r];
            s += __shfl_xor(s, 1);
            s += __shfl_xor(s, 2);
            s += __shfl_xor(s, 4);
            s += __shfl_xor(s, 8);
            if (l == 0) ssb[wave][rt * 16 + g * 4 + r] = s;
        }
    __syncthreads();

    unsigned short* P = isQ ? Qb : Db;
    #pragma unroll
    for (int rt = 0; rt < 2; ++rt)
        #pragma unroll
        for (int r = 0; r < 4; ++r) {
            const int idx = rt * 16 + g * 4 + r;
            const int row = prow + rw + idx;
            float rn = rsqrtf(ssb[wave][idx] + ssb[wave ^ 2][idx]);
            if (!isQ && dmask[row] == 0) rn = 0.f;   // zero masked doc tokens
            #pragma unroll
            for (int n = 0; n < 4; ++n)
                P[(size_t)row * 128 + dn + n * 16 + l] =
                    (unsigned short)f2bf(acc[rt][n][r] * rn);
        }
}

// ---------------------------------------------------------------------------
// Kernel 1.5 (unchanged): in-place per-doc compaction of Db; valid rows first,
// padding duplicates token 0 (always valid; duplicates can't change a max).
// ---------------------------------------------------------------------------
__global__ __launch_bounds__(256) void compact_kernel(
    const int* __restrict__ dmask, unsigned short* __restrict__ Db)
{
    __shared__ __align__(16) short rows[256][128];
    __shared__ int wcnt[4];

    const int c = blockIdx.x;
    const int tid = threadIdx.x;
    const int wave = tid >> 6, lane = tid & 63;

    short8* ldsf = reinterpret_cast<short8*>(&rows[0][0]);
    const short8* src = reinterpret_cast<const short8*>(Db + (size_t)c * 256 * 128);
    #pragma unroll
    for (int i = 0; i < 16; ++i) {
        int idx = i * 256 + tid;
        int row = idx >> 4, ch = idx & 15;
        ldsf[row * 16 + (ch ^ (row & 15))] = src[idx];
    }

    const bool valid = dmask[c * 256 + tid] != 0;
    unsigned long long bal = __ballot(valid);
    const int before = __popcll(bal & ((1ull << lane) - 1ull));
    if (lane == 0) wcnt[wave] = __popcll(bal);
    __syncthreads();

    int base = 0, nv = 0;
    #pragma unroll
    for (int w = 0; w < 4; ++w) { int v = wcnt[w]; nv += v; if (w < wave) base += v; }
    const int myrank = valid ? (base + before) : (nv + (tid - base - before));
    const int srcrow = valid ? tid : 0;

    short8* dst = reinterpret_cast<short8*>(Db + (size_t)(c * 256 + myrank) * 128);
    #pragma unroll
    for (int i = 0; i < 16; ++i)
        dst[i] = *reinterpret_cast<const short8*>(&rows[srcrow][(i ^ (srcrow & 15)) * 8]);
}

// ---------------------------------------------------------------------------
// Kernel 2 (unchanged): out[b][c] = sum_q max_k Q[b,q,:] . Dc[c,k,:]
// Operand-swapped 32x32x16 (A=D tokens, B=Q): max over tokens is IN-LANE.
// ---------------------------------------------------------------------------
__global__ __launch_bounds__(512) void maxsim_kernel(
    const unsigned short* __restrict__ Qb, const unsigned short* __restrict__ Db,
    const int* __restrict__ dmask, float* __restrict__ out)
{
    __shared__ __align__(16) short Dlds[256][128];
    __shared__ int wcnt[4];

    const int tid = threadIdx.x;
    const int wave = tid >> 6, lane = tid & 63;
    const int lo5 = lane & 31, hi = lane >> 5;
    const int c  = blockIdx.x & 127;
    const int bg = blockIdx.x >> 7;
    const int b  = bg * 8 + wave;

    {
        const short8* src = reinterpret_cast<const short8*>(Db + (size_t)c * 256 * 128);
        #pragma unroll
        for (int i = 0; i < 8; ++i) {
            int idx = i * 512 + tid;
            int row = idx >> 4, ch = idx & 15;
            short8 v = src[row * 16 + (ch ^ (row & 15))];
            *reinterpret_cast<short8*>(&Dlds[row][ch * 8]) = v;
        }
    }
    if (tid < 256) {
        bool valid = dmask[c * 256 + tid] != 0;
        unsigned long long bal = __ballot(valid);
        if (lane == 0) wcnt[wave] = __popcll(bal);
    }
    __syncthreads();
    const int nv = wcnt[0] + wcnt[1] + wcnt[2] + wcnt[3];
    const int npairs = (nv + 63) >> 6;

    short8 a[8];
    const unsigned short* qp = Qb + ((size_t)b * 32 + lo5) * 128 + hi * 8;
    #pragma unroll
    for (int ks = 0; ks < 8; ++ks)
        a[ks] = *reinterpret_cast<const short8*>(qp + ks * 16);

    const int sw = lo5 & 15;
    float m = -1e30f;

    for (int p = 0; p < npairs; ++p) {
        f32x16 acc0 = (f32x16)(0.0f), acc1 = (f32x16)(0.0f);
        #pragma unroll
        for (int ks = 0; ks < 8; ++ks) {
            const int chs = ((2 * ks + hi) ^ sw) * 8;
            short8 d0 = *reinterpret_cast<const short8*>(&Dlds[p * 64 + lo5][chs]);
            short8 d1 = *reinterpret_cast<const short8*>(&Dlds[p * 64 + 32 + lo5][chs]);
            acc0 = MFMA32(d0, a[ks], acc0);
            acc1 = MFMA32(d1, a[ks], acc1);
        }
        #pragma unroll
        for (int r = 0; r < 16; ++r)
            m = fmaxf(m, fmaxf(acc0[r], acc1[r]));
    }

    m = fmaxf(m, __shfl_xor(m, 32));
    float s = m;
    s += __shfl_xor(s, 1);
    s += __shfl_xor(s, 2);
    s += __shfl_xor(s, 4);
    s += __shfl_xor(s, 8);
    s += __shfl_xor(s, 16);
    if (lane == 0) out[b * 128 + c] = s;
}

extern "C" void kernel_launch(void* const* d_in, const int* in_sizes, int n_in,
                              void* d_out, int out_size, void* d_ws, size_t ws_size,
                              hipStream_t stream)
{
    const float* qh    = (const float*)d_in[0];   // [128,32,768]
    const float* dh    = (const float*)d_in[1];   // [128,256,768]
    const float* W     = (const float*)d_in[2];   // [128,768]
    const int*   dmask = (const int*)d_in[3];     // [128,256]
    float* out = (float*)d_out;                   // [128,128]

    unsigned short* Qb   = (unsigned short*)d_ws;       // 4096x128 bf16 (1 MB)
    unsigned short* Db   = Qb + 4096 * 128;             // 32768x128 bf16 (8 MB)
    unsigned short* Wimg = Db + (size_t)32768 * 128;    // 196 KB
    unsigned short* Xbf  = Wimg + 12288 * 8;            // 36864x768 bf16 (56.6 MB)

    hipLaunchKernelGGL(cvt_kernel, dim3(1728), dim3(256), 0, stream, qh, dh, Xbf);
    hipLaunchKernelGGL(wprep_kernel, dim3(48), dim3(256), 0, stream, W, Wimg);
    hipLaunchKernelGGL(proj_norm_kernel, dim3(576), dim3(256), 0, stream,
                       Xbf, Wimg, dmask, Qb, Db);
    hipLaunchKernelGGL(compact_kernel, dim3(128), dim3(256), 0, stream,
                       dmask, Db);
    hipLaunchKernelGGL(maxsim_kernel, dim3(2048), dim3(512), 0, stream,
                       Qb, Db, dmask, out);
}

// Round 12
// 84.479 us; speedup vs baseline: 1.0131x; 1.0131x over previous
//
#include <hip/hip_runtime.h>
#include <hip/hip_bf16.h>

// B=128, LQ=32, LD=256, HID=768, DIM=128
typedef __attribute__((ext_vector_type(8))) short short8;
typedef __attribute__((ext_vector_type(4))) float f32x4;
typedef __attribute__((ext_vector_type(16))) float f32x16;

#define MFMA16(a, b, c) __builtin_amdgcn_mfma_f32_16x16x32_bf16(a, b, c, 0, 0, 0)
#define MFMA32(a, b, c) __builtin_amdgcn_mfma_f32_32x32x16_bf16(a, b, c, 0, 0, 0)
#define RAW_BAR() do { __builtin_amdgcn_sched_barrier(0); \
                       __builtin_amdgcn_s_barrier(); \
                       __builtin_amdgcn_sched_barrier(0); } while (0)
#define VMCNT(n) do { asm volatile("s_waitcnt vmcnt(" #n ")" ::: "memory"); \
                      __builtin_amdgcn_sched_barrier(0); } while (0)

__device__ __forceinline__ short f2bf(float f) {
    union { float f; unsigned u; } x; x.f = f;
    unsigned r = x.u + 0x7fffu + ((x.u >> 16) & 1u);  // RNE
    return (short)(r >> 16);
}

__device__ __forceinline__ short8 cvt8(const float4& a, const float4& b) {
    short8 v;
    v[0]=f2bf(a.x); v[1]=f2bf(a.y); v[2]=f2bf(a.z); v[3]=f2bf(a.w);
    v[4]=f2bf(b.x); v[5]=f2bf(b.y); v[6]=f2bf(b.z); v[7]=f2bf(b.w);
    return v;
}

// ---------------------------------------------------------------------------
// Kernel A: streaming cvt, MASK-SKIPPING. Xbf[row][768] bf16 <- concat(qh,dh).
// Masked doc rows are skipped entirely (proj zeroes them via rn=0; their Xbf
// bytes stay 0xAA poison = finite tiny bf16 -> no NaN). Saves ~48 MB read.
// Wave covers 2 rows (32 lanes/row, 512B contiguous per group, coalesced).
// ---------------------------------------------------------------------------
__global__ __launch_bounds__(256) void cvt_kernel(
    const float* __restrict__ qh, const float* __restrict__ dh,
    const int* __restrict__ dmask, unsigned short* __restrict__ Xbf)
{
    const int tid = threadIdx.x;
    const int row = blockIdx.x * 8 + (tid >> 5);     // 0..36863 (Q first 4096)
    const int j0 = tid & 31;
    const bool isQ = row < 4096;
    if (!isQ && dmask[row - 4096] == 0) return;      // skip masked doc rows
    const float* src = isQ ? qh + (size_t)row * 768
                           : dh + (size_t)(row - 4096) * 768;
    unsigned short* dst = Xbf + (size_t)row * 768;
    #pragma unroll
    for (int i = 0; i < 3; ++i) {
        const int c = j0 + i * 32;                   // chunk of 8 elems
        float4 a = reinterpret_cast<const float4*>(src + c * 8)[0];
        float4 b = reinterpret_cast<const float4*>(src + c * 8)[1];
        *reinterpret_cast<short8*>(dst + c * 8) = cvt8(a, b);
    }
}

// ---------------------------------------------------------------------------
// Kernel 0 (unchanged): W [128x768] fp32 -> bf16 B-fragment image, 16x16x32.
// Slot gt = (kc*16 + f)*64 + lane, f = ks*8 + dimt:
//   dim = (f&7)*16 + (lane&15), k = kc*64 + (f>>3)*32 + (lane>>4)*8 + j.
// ---------------------------------------------------------------------------
__global__ __launch_bounds__(256) void wprep_kernel(
    const float* __restrict__ W, unsigned short* __restrict__ Wimg)
{
    const int gt = blockIdx.x * 256 + threadIdx.x;    // 0..12287
    const int kc = gt >> 10, rem = gt & 1023;
    const int f = rem >> 6, lane = rem & 63;
    const int dim = (f & 7) * 16 + (lane & 15);
    const int kb  = kc * 64 + (f >> 3) * 32 + (lane >> 4) * 8;
    const float4* s = reinterpret_cast<const float4*>(W + dim * 768 + kb);
    float4 a = s[0], b = s[1];
    *reinterpret_cast<short8*>(Wimg + (size_t)gt * 8) = cvt8(a, b);
}

// ---------------------------------------------------------------------------
// Kernel 1: P[row][dim] = l2norm(Xbf[row] @ W^T), bf16 out. ALL-bf16 GEMM.
// 3-BUFFER pipeline with COUNTED vmcnt(6) (T3/T4): loads issued 2 tiles
// ahead get TWO compute phases (~1200cy) to cover HBM latency (~900cy) ->
// zero steady-state stall; barrier never drains in-flight prefetch.
// Per wave per tile: 6 gld_lds (2 X + 4 W) -> vmcnt(6) == prev tile landed.
// ---------------------------------------------------------------------------
__global__ __launch_bounds__(256) void proj_norm_kernel(
    const unsigned short* __restrict__ Xbf, const unsigned short* __restrict__ Wimg,
    const int* __restrict__ dmask,
    unsigned short* __restrict__ Qb, unsigned short* __restrict__ Db)
{
    __shared__ __align__(16) short Xl[3][4096];     // 24 KB (swz bf16 X tiles)
    __shared__ __align__(16) short Wl[3][8192];     // 48 KB (frag image, linear)
    __shared__ float ssb[4][32];

    const int tid = threadIdx.x;
    const int wave = tid >> 6, lane = tid & 63;
    const int l = lane & 15, g = lane >> 4;
    const int rw = (wave & 1) * 32;                 // wave's row base
    const int dn4 = (wave >> 1) * 4;                // wave's dim-tile base
    const int dn = dn4 * 16;

    const int rowbase = blockIdx.x * 64;            // into combined Xbf
    const bool isQ = rowbase < 4096;
    const int prow = isQ ? rowbase : rowbase - 4096;

    auto xstage = [&](int t, int p) {               // 2 gld_lds/wave
        #pragma unroll
        for (int i = 0; i < 2; ++i) {
            const int c8 = i * 256 + tid;           // 16B-chunk: row=c8>>3, cl=c8&7
            const int row = c8 >> 3, cl = c8 & 7;
            const unsigned short* src =
                Xbf + (size_t)(rowbase + row) * 768 + t * 64 + ((cl ^ (row & 7)) * 8);
            __builtin_amdgcn_global_load_lds(
                (const __attribute__((address_space(1))) void*)src,
                (__attribute__((address_space(3))) void*)(&Xl[p][i * 2048 + wave * 512]),
                16, 0, 0);
        }
    };
    auto wstage = [&](int t, int p) {               // 4 gld_lds/wave
        const unsigned short* src = Wimg + (size_t)t * 8192 + wave * 2048 + lane * 8;
        #pragma unroll
        for (int i = 0; i < 4; ++i)
            __builtin_amdgcn_global_load_lds(
                (const __attribute__((address_space(1))) void*)(src + i * 512),
                (__attribute__((address_space(3))) void*)(&Wl[p][wave * 2048 + i * 512]),
                16, 0, 0);
    };

    f32x4 acc[2][4];
    #pragma unroll
    for (int rt = 0; rt < 2; ++rt)
        #pragma unroll
        for (int n = 0; n < 4; ++n) acc[rt][n] = (f32x4)(0.0f);

    auto compute = [&](int p) {
        #pragma unroll
        for (int ks = 0; ks < 2; ++ks) {
            short8 af[2];
            #pragma unroll
            for (int rt = 0; rt < 2; ++rt) {
                const int row = rw + rt * 16 + l;
                const int c = (ks * 4 + g) ^ (row & 7);       // swizzled read
                af[rt] = *reinterpret_cast<const short8*>(&Xl[p][row * 64 + c * 8]);
            }
            #pragma unroll
            for (int n = 0; n < 4; ++n) {
                short8 bf = *reinterpret_cast<const short8*>(
                    &Wl[p][(ks * 8 + dn4 + n) * 512 + lane * 8]);
                acc[0][n] = MFMA16(af[0], bf, acc[0][n]);
                acc[1][n] = MFMA16(af[1], bf, acc[1][n]);
            }
        }
    };

    // prologue: tiles 0,1 in flight; wait tile 0 only (vmcnt 6 = tile 1 flying)
    xstage(0, 0); wstage(0, 0);
    xstage(1, 1); wstage(1, 1);
    VMCNT(6); RAW_BAR();

    for (int t = 0; t < 12; ++t) {
        const int p = t % 3;
        if (t < 10) { xstage(t + 2, (t + 2) % 3); wstage(t + 2, (t + 2) % 3); }
        compute(p);
        if (t < 11) {
            if (t < 10) { VMCNT(6); }   // tile t+1 landed; t+2 still flying
            else        { VMCNT(0); }   // last prefetch (tile 11) must land
            RAW_BAR();
        }
    }

    // --- L2 norm: acc[rt][n][r] = C[row=rw+rt*16+g*4+r][dim=dn+n*16+l] ---
    #pragma unroll
    for (int rt = 0; rt < 2; ++rt)
        #pragma unroll
        for (int r = 0; r < 4; ++r) {
            float s = 0.f;
            #pragma unroll
            for (int n = 0; n < 4; ++n) s += acc[rt][n][r] * acc[rt][n][r];
            s += __shfl_xor(s, 1);
            s += __shfl_xor(s, 2);
            s += __shfl_xor(s, 4);
            s += __shfl_xor(s, 8);
            if (l == 0) ssb[wave][rt * 16 + g * 4 + r] = s;
        }
    __syncthreads();

    unsigned short* P = isQ ? Qb : Db;
    #pragma unroll
    for (int rt = 0; rt < 2; ++rt)
        #pragma unroll
        for (int r = 0; r < 4; ++r) {
            const int idx = rt * 16 + g * 4 + r;
            const int row = prow + rw + idx;
            float rn = rsqrtf(ssb[wave][idx] + ssb[wave ^ 2][idx]);
            if (!isQ && dmask[row] == 0) rn = 0.f;   // zero masked doc tokens
            #pragma unroll
            for (int n = 0; n < 4; ++n)
                P[(size_t)row * 128 + dn + n * 16 + l] =
                    (unsigned short)f2bf(acc[rt][n][r] * rn);
        }
}

// ---------------------------------------------------------------------------
// Kernel 1.5 (unchanged): in-place per-doc compaction of Db; valid rows first,
// padding duplicates token 0 (always valid; duplicates can't change a max).
// ---------------------------------------------------------------------------
__global__ __launch_bounds__(256) void compact_kernel(
    const int* __restrict__ dmask, unsigned short* __restrict__ Db)
{
    __shared__ __align__(16) short rows[256][128];
    __shared__ int wcnt[4];

    const int c = blockIdx.x;
    const int tid = threadIdx.x;
    const int wave = tid >> 6, lane = tid & 63;

    short8* ldsf = reinterpret_cast<short8*>(&rows[0][0]);
    const short8* src = reinterpret_cast<const short8*>(Db + (size_t)c * 256 * 128);
    #pragma unroll
    for (int i = 0; i < 16; ++i) {
        int idx = i * 256 + tid;
        int row = idx >> 4, ch = idx & 15;
        ldsf[row * 16 + (ch ^ (row & 15))] = src[idx];
    }

    const bool valid = dmask[c * 256 + tid] != 0;
    unsigned long long bal = __ballot(valid);
    const int before = __popcll(bal & ((1ull << lane) - 1ull));
    if (lane == 0) wcnt[wave] = __popcll(bal);
    __syncthreads();

    int base = 0, nv = 0;
    #pragma unroll
    for (int w = 0; w < 4; ++w) { int v = wcnt[w]; nv += v; if (w < wave) base += v; }
    const int myrank = valid ? (base + before) : (nv + (tid - base - before));
    const int srcrow = valid ? tid : 0;

    short8* dst = reinterpret_cast<short8*>(Db + (size_t)(c * 256 + myrank) * 128);
    #pragma unroll
    for (int i = 0; i < 16; ++i)
        dst[i] = *reinterpret_cast<const short8*>(&rows[srcrow][(i ^ (srcrow & 15)) * 8]);
}

// ---------------------------------------------------------------------------
// Kernel 2 (unchanged): out[b][c] = sum_q max_k Q[b,q,:] . Dc[c,k,:]
// Operand-swapped 32x32x16 (A=D tokens, B=Q): max over tokens is IN-LANE.
// ---------------------------------------------------------------------------
__global__ __launch_bounds__(512) void maxsim_kernel(
    const unsigned short* __restrict__ Qb, const unsigned short* __restrict__ Db,
    const int* __restrict__ dmask, float* __restrict__ out)
{
    __shared__ __align__(16) short Dlds[256][128];
    __shared__ int wcnt[4];

    const int tid = threadIdx.x;
    const int wave = tid >> 6, lane = tid & 63;
    const int lo5 = lane & 31, hi = lane >> 5;
    const int c  = blockIdx.x & 127;
    const int bg = blockIdx.x >> 7;
    const int b  = bg * 8 + wave;

    {
        const short8* src = reinterpret_cast<const short8*>(Db + (size_t)c * 256 * 128);
        #pragma unroll
        for (int i = 0; i < 8; ++i) {
            int idx = i * 512 + tid;
            int row = idx >> 4, ch = idx & 15;
            short8 v = src[row * 16 + (ch ^ (row & 15))];
            *reinterpret_cast<short8*>(&Dlds[row][ch * 8]) = v;
        }
    }
    if (tid < 256) {
        bool valid = dmask[c * 256 + tid] != 0;
        unsigned long long bal = __ballot(valid);
        if (lane == 0) wcnt[wave] = __popcll(bal);
    }
    __syncthreads();
    const int nv = wcnt[0] + wcnt[1] + wcnt[2] + wcnt[3];
    const int npairs = (nv + 63) >> 6;

    short8 a[8];
    const unsigned short* qp = Qb + ((size_t)b * 32 + lo5) * 128 + hi * 8;
    #pragma unroll
    for (int ks = 0; ks < 8; ++ks)
        a[ks] = *reinterpret_cast<const short8*>(qp + ks * 16);

    const int sw = lo5 & 15;
    float m = -1e30f;

    for (int p = 0; p < npairs; ++p) {
        f32x16 acc0 = (f32x16)(0.0f), acc1 = (f32x16)(0.0f);
        #pragma unroll
        for (int ks = 0; ks < 8; ++ks) {
            const int chs = ((2 * ks + hi) ^ sw) * 8;
            short8 d0 = *reinterpret_cast<const short8*>(&Dlds[p * 64 + lo5][chs]);
            short8 d1 = *reinterpret_cast<const short8*>(&Dlds[p * 64 + 32 + lo5][chs]);
            acc0 = MFMA32(d0, a[ks], acc0);
            acc1 = MFMA32(d1, a[ks], acc1);
        }
        #pragma unroll
        for (int r = 0; r < 16; ++r)
            m = fmaxf(m, fmaxf(acc0[r], acc1[r]));
    }

    m = fmaxf(m, __shfl_xor(m, 32));
    float s = m;
    s += __shfl_xor(s, 1);
    s += __shfl_xor(s, 2);
    s += __shfl_xor(s, 4);
    s += __shfl_xor(s, 8);
    s += __shfl_xor(s, 16);
    if (lane == 0) out[b * 128 + c] = s;
}

extern "C" void kernel_launch(void* const* d_in, const int* in_sizes, int n_in,
                              void* d_out, int out_size, void* d_ws, size_t ws_size,
                              hipStream_t stream)
{
    const float* qh    = (const float*)d_in[0];   // [128,32,768]
    const float* dh    = (const float*)d_in[1];   // [128,256,768]
    const float* W     = (const float*)d_in[2];   // [128,768]
    const int*   dmask = (const int*)d_in[3];     // [128,256]
    float* out = (float*)d_out;                   // [128,128]

    unsigned short* Qb   = (unsigned short*)d_ws;       // 4096x128 bf16 (1 MB)
    unsigned short* Db   = Qb + 4096 * 128;             // 32768x128 bf16 (8 MB)
    unsigned short* Wimg = Db + (size_t)32768 * 128;    // 196 KB
    unsigned short* Xbf  = Wimg + 12288 * 8;            // 36864x768 bf16 (56.6 MB)

    hipLaunchKernelGGL(cvt_kernel, dim3(4608), dim3(256), 0, stream,
                       qh, dh, dmask, Xbf);
    hipLaunchKernelGGL(wprep_kernel, dim3(48), dim3(256), 0, stream, W, Wimg);
    hipLaunchKernelGGL(proj_norm_kernel, dim3(576), dim3(256), 0, stream,
                       Xbf, Wimg, dmask, Qb, Db);
    hipLaunchKernelGGL(compact_kernel, dim3(128), dim3(256), 0, stream,
                       dmask, Db);
    hipLaunchKernelGGL(maxsim_kernel, dim3(2048), dim3(512), 0, stream,
                       Qb, Db, dmask, out);
}

// Round 13
// 79.978 us; speedup vs baseline: 1.0701x; 1.0563x over previous
//
#include <hip/hip_runtime.h>
#include <hip/hip_bf16.h>

// B=128, LQ=32, LD=256, HID=768, DIM=128
typedef __attribute__((ext_vector_type(8))) short short8;
typedef __attribute__((ext_vector_type(4))) float f32x4;
typedef __attribute__((ext_vector_type(16))) float f32x16;

#define MFMA16(a, b, c) __builtin_amdgcn_mfma_f32_16x16x32_bf16(a, b, c, 0, 0, 0)
#define MFMA32(a, b, c) __builtin_amdgcn_mfma_f32_32x32x16_bf16(a, b, c, 0, 0, 0)
#define RAW_BAR() do { __builtin_amdgcn_sched_barrier(0); \
                       __builtin_amdgcn_s_barrier(); \
                       __builtin_amdgcn_sched_barrier(0); } while (0)
#define VMCNT(n) do { asm volatile("s_waitcnt vmcnt(" #n ")" ::: "memory"); \
                      __builtin_amdgcn_sched_barrier(0); } while (0)

__device__ __forceinline__ short f2bf(float f) {
    union { float f; unsigned u; } x; x.f = f;
    unsigned r = x.u + 0x7fffu + ((x.u >> 16) & 1u);  // RNE
    return (short)(r >> 16);
}

__device__ __forceinline__ short8 cvt8(const float4& a, const float4& b) {
    short8 v;
    v[0]=f2bf(a.x); v[1]=f2bf(a.y); v[2]=f2bf(a.z); v[3]=f2bf(a.w);
    v[4]=f2bf(b.x); v[5]=f2bf(b.y); v[6]=f2bf(b.z); v[7]=f2bf(b.w);
    return v;
}

// ---------------------------------------------------------------------------
// Kernel P: blocks 0..47 = wprep (W -> bf16 16x16x32 frag image);
// blocks 48..175 = per-doc mask scan: rowmap[c*256+slot] = source token for
// each compacted slot (valid tokens in order, then token-0 duplicates up to
// npairs*64); nvb[c] = npairs = ceil(nv/64). Replaces the compact kernel.
// ---------------------------------------------------------------------------
__global__ __launch_bounds__(256) void prep_kernel(
    const float* __restrict__ W, const int* __restrict__ dmask,
    unsigned short* __restrict__ Wimg, int* __restrict__ rowmap,
    int* __restrict__ nvb)
{
    __shared__ int wcnt[4];
    const int tid = threadIdx.x;

    if (blockIdx.x < 48) {          // --- wprep ---
        const int gt = blockIdx.x * 256 + tid;            // 0..12287
        const int kc = gt >> 10, rem = gt & 1023;
        const int f = rem >> 6, lane = rem & 63;
        const int dim = (f & 7) * 16 + (lane & 15);
        const int kb  = kc * 64 + (f >> 3) * 32 + (lane >> 4) * 8;
        const float4* s = reinterpret_cast<const float4*>(W + dim * 768 + kb);
        float4 a = s[0], b = s[1];
        *reinterpret_cast<short8*>(Wimg + (size_t)gt * 8) = cvt8(a, b);
        return;
    }

    // --- mask scan for doc c ---
    const int c = blockIdx.x - 48;
    const int wave = tid >> 6, lane = tid & 63;
    const bool valid = dmask[c * 256 + tid] != 0;
    unsigned long long bal = __ballot(valid);
    const int before = __popcll(bal & ((1ull << lane) - 1ull));
    if (lane == 0) wcnt[wave] = __popcll(bal);
    __syncthreads();
    int base = 0, nv = 0;
    #pragma unroll
    for (int w = 0; w < 4; ++w) { int v = wcnt[w]; nv += v; if (w < wave) base += v; }
    const int rank = valid ? (base + before) : (nv + (tid - base - before));
    const int npairs = (nv + 63) >> 6;
    if (rank < npairs * 64) rowmap[c * 256 + rank] = valid ? tid : 0;
    if (tid == 0) nvb[c] = npairs;
}

// ---------------------------------------------------------------------------
// Kernel A: streaming cvt via rowmap GATHER. Xbf row r:
//   r < 4096          : Q row r
//   r = 4096+c*256+s  : doc c, compacted slot s (skip s >= npairs*64)
// Only ~20.5K of 36.9K rows are materialized.
// ---------------------------------------------------------------------------
__global__ __launch_bounds__(256) void cvt_kernel(
    const float* __restrict__ qh, const float* __restrict__ dh,
    const int* __restrict__ rowmap, const int* __restrict__ nvb,
    unsigned short* __restrict__ Xbf)
{
    const int tid = threadIdx.x;
    const int row = blockIdx.x * 8 + (tid >> 5);     // 0..36863
    const int j0 = tid & 31;
    const float* src;
    if (row < 4096) {
        src = qh + (size_t)row * 768;
    } else {
        const int gr = row - 4096, c = gr >> 8, slot = gr & 255;
        if (slot >= (nvb[c] << 6)) return;           // beyond padding: skip
        src = dh + ((size_t)c * 256 + rowmap[gr]) * 768;
    }
    unsigned short* dst = Xbf + (size_t)row * 768;
    #pragma unroll
    for (int i = 0; i < 3; ++i) {
        const int ch = j0 + i * 32;                  // chunk of 8 elems
        float4 a = reinterpret_cast<const float4*>(src + ch * 8)[0];
        float4 b = reinterpret_cast<const float4*>(src + ch * 8)[1];
        *reinterpret_cast<short8*>(dst + ch * 8) = cvt8(a, b);
    }
}

// ---------------------------------------------------------------------------
// Kernel 1: P[row][dim] = l2norm(Xbf[row] @ W^T), bf16, COMPACTED rows only.
// Doc blocks beyond their doc's npairs exit immediately (uniform branch).
// No mask logic in epilogue: every staged slot is a valid token or a
// token-0 duplicate (duplicates cannot change a max downstream).
// 3-buffer gld_lds pipeline with counted vmcnt(6) (unchanged from R12).
// ---------------------------------------------------------------------------
__global__ __launch_bounds__(256) void proj_norm_kernel(
    const unsigned short* __restrict__ Xbf, const unsigned short* __restrict__ Wimg,
    const int* __restrict__ nvb,
    unsigned short* __restrict__ Qb, unsigned short* __restrict__ Db)
{
    __shared__ __align__(16) short Xl[3][4096];     // 24 KB (swz bf16 X tiles)
    __shared__ __align__(16) short Wl[3][8192];     // 48 KB (frag image, linear)
    __shared__ float ssb[4][32];

    const int rowbase = blockIdx.x * 64;            // into Xbf row space
    const bool isQ = rowbase < 4096;
    if (!isQ) {
        const int gr = rowbase - 4096;
        if (((gr >> 6) & 3) >= nvb[gr >> 8]) return;   // block beyond padding
    }
    const int prow = isQ ? rowbase : rowbase - 4096;

    const int tid = threadIdx.x;
    const int wave = tid >> 6, lane = tid & 63;
    const int l = lane & 15, g = lane >> 4;
    const int rw = (wave & 1) * 32;
    const int dn4 = (wave >> 1) * 4;
    const int dn = dn4 * 16;

    auto xstage = [&](int t, int p) {               // 2 gld_lds/wave
        #pragma unroll
        for (int i = 0; i < 2; ++i) {
            const int c8 = i * 256 + tid;           // 16B-chunk: row=c8>>3, cl=c8&7
            const int row = c8 >> 3, cl = c8 & 7;
            const unsigned short* src =
                Xbf + (size_t)(rowbase + row) * 768 + t * 64 + ((cl ^ (row & 7)) * 8);
            __builtin_amdgcn_global_load_lds(
                (const __attribute__((address_space(1))) void*)src,
                (__attribute__((address_space(3))) void*)(&Xl[p][i * 2048 + wave * 512]),
                16, 0, 0);
        }
    };
    auto wstage = [&](int t, int p) {               // 4 gld_lds/wave
        const unsigned short* src = Wimg + (size_t)t * 8192 + wave * 2048 + lane * 8;
        #pragma unroll
        for (int i = 0; i < 4; ++i)
            __builtin_amdgcn_global_load_lds(
                (const __attribute__((address_space(1))) void*)(src + i * 512),
                (__attribute__((address_space(3))) void*)(&Wl[p][wave * 2048 + i * 512]),
                16, 0, 0);
    };

    f32x4 acc[2][4];
    #pragma unroll
    for (int rt = 0; rt < 2; ++rt)
        #pragma unroll
        for (int n = 0; n < 4; ++n) acc[rt][n] = (f32x4)(0.0f);

    auto compute = [&](int p) {
        #pragma unroll
        for (int ks = 0; ks < 2; ++ks) {
            short8 af[2];
            #pragma unroll
            for (int rt = 0; rt < 2; ++rt) {
                const int row = rw + rt * 16 + l;
                const int c = (ks * 4 + g) ^ (row & 7);       // swizzled read
                af[rt] = *reinterpret_cast<const short8*>(&Xl[p][row * 64 + c * 8]);
            }
            #pragma unroll
            for (int n = 0; n < 4; ++n) {
                short8 bf = *reinterpret_cast<const short8*>(
                    &Wl[p][(ks * 8 + dn4 + n) * 512 + lane * 8]);
                acc[0][n] = MFMA16(af[0], bf, acc[0][n]);
                acc[1][n] = MFMA16(af[1], bf, acc[1][n]);
            }
        }
    };

    xstage(0, 0); wstage(0, 0);
    xstage(1, 1); wstage(1, 1);
    VMCNT(6); RAW_BAR();

    for (int t = 0; t < 12; ++t) {
        const int p = t % 3;
        if (t < 10) { xstage(t + 2, (t + 2) % 3); wstage(t + 2, (t + 2) % 3); }
        compute(p);
        if (t < 11) {
            if (t < 10) { VMCNT(6); }
            else        { VMCNT(0); }
            RAW_BAR();
        }
    }

    // --- L2 norm: acc[rt][n][r] = C[row=rw+rt*16+g*4+r][dim=dn+n*16+l] ---
    #pragma unroll
    for (int rt = 0; rt < 2; ++rt)
        #pragma unroll
        for (int r = 0; r < 4; ++r) {
            float s = 0.f;
            #pragma unroll
            for (int n = 0; n < 4; ++n) s += acc[rt][n][r] * acc[rt][n][r];
            s += __shfl_xor(s, 1);
            s += __shfl_xor(s, 2);
            s += __shfl_xor(s, 4);
            s += __shfl_xor(s, 8);
            if (l == 0) ssb[wave][rt * 16 + g * 4 + r] = s;
        }
    __syncthreads();

    unsigned short* P = isQ ? Qb : Db;
    #pragma unroll
    for (int rt = 0; rt < 2; ++rt)
        #pragma unroll
        for (int r = 0; r < 4; ++r) {
            const int idx = rt * 16 + g * 4 + r;
            const int row = prow + rw + idx;
            const float rn = rsqrtf(ssb[wave][idx] + ssb[wave ^ 2][idx]);
            #pragma unroll
            for (int n = 0; n < 4; ++n)
                P[(size_t)row * 128 + dn + n * 16 + l] =
                    (unsigned short)f2bf(acc[rt][n][r] * rn);
        }
}

// ---------------------------------------------------------------------------
// Kernel 2: out[b][c] = sum_q max_k Q[b,q,:] . Dc[c,k,:]  (Dc pre-compacted)
// Operand-swapped 32x32x16 (A=D tokens, B=Q): max over tokens is IN-LANE.
// npairs read from nvb (ballot-count removed); stages only npairs*64 rows.
// ---------------------------------------------------------------------------
__global__ __launch_bounds__(512) void maxsim_kernel(
    const unsigned short* __restrict__ Qb, const unsigned short* __restrict__ Db,
    const int* __restrict__ nvb, float* __restrict__ out)
{
    __shared__ __align__(16) short Dlds[256][128];

    const int tid = threadIdx.x;
    const int wave = tid >> 6, lane = tid & 63;
    const int lo5 = lane & 31, hi = lane >> 5;
    const int c  = blockIdx.x & 127;
    const int bg = blockIdx.x >> 7;
    const int b  = bg * 8 + wave;

    const int npairs = nvb[c];                       // 1..4

    {
        const short8* src = reinterpret_cast<const short8*>(Db + (size_t)c * 256 * 128);
        #pragma unroll
        for (int i = 0; i < 8; ++i) {
            if (i * 32 >= npairs * 64) break;        // uniform: skip unused rows
            int idx = i * 512 + tid;
            int row = idx >> 4, ch = idx & 15;
            short8 v = src[row * 16 + (ch ^ (row & 15))];
            *reinterpret_cast<short8*>(&Dlds[row][ch * 8]) = v;
        }
    }
    __syncthreads();

    short8 a[8];
    const unsigned short* qp = Qb + ((size_t)b * 32 + lo5) * 128 + hi * 8;
    #pragma unroll
    for (int ks = 0; ks < 8; ++ks)
        a[ks] = *reinterpret_cast<const short8*>(qp + ks * 16);

    const int sw = lo5 & 15;
    float m = -1e30f;

    for (int p = 0; p < npairs; ++p) {
        f32x16 acc0 = (f32x16)(0.0f), acc1 = (f32x16)(0.0f);
        #pragma unroll
        for (int ks = 0; ks < 8; ++ks) {
            const int chs = ((2 * ks + hi) ^ sw) * 8;
            short8 d0 = *reinterpret_cast<const short8*>(&Dlds[p * 64 + lo5][chs]);
            short8 d1 = *reinterpret_cast<const short8*>(&Dlds[p * 64 + 32 + lo5][chs]);
            acc0 = MFMA32(d0, a[ks], acc0);
            acc1 = MFMA32(d1, a[ks], acc1);
        }
        #pragma unroll
        for (int r = 0; r < 16; ++r)
            m = fmaxf(m, fmaxf(acc0[r], acc1[r]));
    }

    m = fmaxf(m, __shfl_xor(m, 32));
    float s = m;
    s += __shfl_xor(s, 1);
    s += __shfl_xor(s, 2);
    s += __shfl_xor(s, 4);
    s += __shfl_xor(s, 8);
    s += __shfl_xor(s, 16);
    if (lane == 0) out[b * 128 + c] = s;
}

extern "C" void kernel_launch(void* const* d_in, const int* in_sizes, int n_in,
                              void* d_out, int out_size, void* d_ws, size_t ws_size,
                              hipStream_t stream)
{
    const float* qh    = (const float*)d_in[0];   // [128,32,768]
    const float* dh    = (const float*)d_in[1];   // [128,256,768]
    const float* W     = (const float*)d_in[2];   // [128,768]
    const int*   dmask = (const int*)d_in[3];     // [128,256]
    float* out = (float*)d_out;                   // [128,128]

    unsigned short* Qb   = (unsigned short*)d_ws;       // 4096x128 bf16 (1 MB)
    unsigned short* Db   = Qb + 4096 * 128;             // 32768x128 bf16 (8 MB)
    unsigned short* Wimg = Db + (size_t)32768 * 128;    // 196 KB
    unsigned short* Xbf  = Wimg + 12288 * 8;            // 36864x768 bf16 (56.6 MB)
    int* rowmap = (int*)(Xbf + (size_t)36864 * 768);    // 32768 ints (128 KB)
    int* nvb    = rowmap + 32768;                       // 128 ints

    hipLaunchKernelGGL(prep_kernel, dim3(176), dim3(256), 0, stream,
                       W, dmask, Wimg, rowmap, nvb);
    hipLaunchKernelGGL(cvt_kernel, dim3(4608), dim3(256), 0, stream,
                       qh, dh, rowmap, nvb, Xbf);
    hipLaunchKernelGGL(proj_norm_kernel, dim3(576), dim3(256), 0, stream,
                       Xbf, Wimg, nvb, Qb, Db);
    hipLaunchKernelGGL(maxsim_kernel, dim3(2048), dim3(512), 0, stream,
                       Qb, Db, nvb, out);
}

// Round 14
// 77.889 us; speedup vs baseline: 1.0988x; 1.0268x over previous
//
#include <hip/hip_runtime.h>
#include <hip/hip_bf16.h>

// B=128, LQ=32, LD=256, HID=768, DIM=128
typedef __attribute__((ext_vector_type(8))) short short8;
typedef __attribute__((ext_vector_type(4))) short short4v;
typedef __attribute__((ext_vector_type(4))) float f32x4;
typedef __attribute__((ext_vector_type(16))) float f32x16;

#define MFMA16(a, b, c) __builtin_amdgcn_mfma_f32_16x16x32_bf16(a, b, c, 0, 0, 0)
#define MFMA32(a, b, c) __builtin_amdgcn_mfma_f32_32x32x16_bf16(a, b, c, 0, 0, 0)
#define RAW_BAR() do { __builtin_amdgcn_sched_barrier(0); \
                       __builtin_amdgcn_s_barrier(); \
                       __builtin_amdgcn_sched_barrier(0); } while (0)
#define VMCNT(n) do { asm volatile("s_waitcnt vmcnt(" #n ")" ::: "memory"); \
                      __builtin_amdgcn_sched_barrier(0); } while (0)

__device__ __forceinline__ short f2bf(float f) {
    union { float f; unsigned u; } x; x.f = f;
    unsigned r = x.u + 0x7fffu + ((x.u >> 16) & 1u);  // RNE
    return (short)(r >> 16);
}

__device__ __forceinline__ short8 cvt8(const float4& a, const float4& b) {
    short8 v;
    v[0]=f2bf(a.x); v[1]=f2bf(a.y); v[2]=f2bf(a.z); v[3]=f2bf(a.w);
    v[4]=f2bf(b.x); v[5]=f2bf(b.y); v[6]=f2bf(b.z); v[7]=f2bf(b.w);
    return v;
}

// ---------------------------------------------------------------------------
// Kernel P (unchanged): blocks 0..47 wprep (W -> 16x16x32 frag image);
// blocks 48..175 per-doc mask scan -> rowmap (compacted slot -> source token,
// pad = token 0) and nvb[c] = npairs = ceil(nv/64).
// ---------------------------------------------------------------------------
__global__ __launch_bounds__(256) void prep_kernel(
    const float* __restrict__ W, const int* __restrict__ dmask,
    unsigned short* __restrict__ Wimg, int* __restrict__ rowmap,
    int* __restrict__ nvb)
{
    __shared__ int wcnt[4];
    const int tid = threadIdx.x;

    if (blockIdx.x < 48) {
        const int gt = blockIdx.x * 256 + tid;            // 0..12287
        const int kc = gt >> 10, rem = gt & 1023;
        const int f = rem >> 6, lane = rem & 63;
        const int dim = (f & 7) * 16 + (lane & 15);
        const int kb  = kc * 64 + (f >> 3) * 32 + (lane >> 4) * 8;
        const float4* s = reinterpret_cast<const float4*>(W + dim * 768 + kb);
        float4 a = s[0], b = s[1];
        *reinterpret_cast<short8*>(Wimg + (size_t)gt * 8) = cvt8(a, b);
        return;
    }

    const int c = blockIdx.x - 48;
    const int wave = tid >> 6, lane = tid & 63;
    const bool valid = dmask[c * 256 + tid] != 0;
    unsigned long long bal = __ballot(valid);
    const int before = __popcll(bal & ((1ull << lane) - 1ull));
    if (lane == 0) wcnt[wave] = __popcll(bal);
    __syncthreads();
    int base = 0, nv = 0;
    #pragma unroll
    for (int w = 0; w < 4; ++w) { int v = wcnt[w]; nv += v; if (w < wave) base += v; }
    const int rank = valid ? (base + before) : (nv + (tid - base - before));
    const int npairs = (nv + 63) >> 6;
    if (rank < npairs * 64) rowmap[c * 256 + rank] = valid ? tid : 0;
    if (tid == 0) nvb[c] = npairs;
}

// ---------------------------------------------------------------------------
// Kernel A (unchanged): streaming cvt via rowmap gather -> Xbf (bf16).
// ---------------------------------------------------------------------------
__global__ __launch_bounds__(256) void cvt_kernel(
    const float* __restrict__ qh, const float* __restrict__ dh,
    const int* __restrict__ rowmap, const int* __restrict__ nvb,
    unsigned short* __restrict__ Xbf)
{
    const int tid = threadIdx.x;
    const int row = blockIdx.x * 8 + (tid >> 5);     // 0..36863
    const int j0 = tid & 31;
    const float* src;
    if (row < 4096) {
        src = qh + (size_t)row * 768;
    } else {
        const int gr = row - 4096, c = gr >> 8, slot = gr & 255;
        if (slot >= (nvb[c] << 6)) return;
        src = dh + ((size_t)c * 256 + rowmap[gr]) * 768;
    }
    unsigned short* dst = Xbf + (size_t)row * 768;
    #pragma unroll
    for (int i = 0; i < 3; ++i) {
        const int ch = j0 + i * 32;
        float4 a = reinterpret_cast<const float4*>(src + ch * 8)[0];
        float4 b = reinterpret_cast<const float4*>(src + ch * 8)[1];
        *reinterpret_cast<short8*>(dst + ch * 8) = cvt8(a, b);
    }
}

// ---------------------------------------------------------------------------
// Kernel 1: K-SPLIT projection partials. Block = (row-block rb, K-half h);
// computes Pp[h][row][dim] (fp32, no norm) over K = h*384..+384.
// BM=64, BK=32 (12 steps), LDS 24 KB -> 6 blocks/CU; ~1280 active blocks
// -> ~5 resident/CU (TLP finally hides latency). Per wave per step exactly
// 3 gld_lds (1 X + 2 W) -> counted VMCNT(3); tile t+1 flies across
// compute + 2 raw barriers. W image contiguous per BK=32 step.
// ---------------------------------------------------------------------------
__global__ __launch_bounds__(256) void proj_half_kernel(
    const unsigned short* __restrict__ Xbf, const unsigned short* __restrict__ Wimg,
    const int* __restrict__ nvb, float* __restrict__ Pp)
{
    __shared__ __align__(16) short Xl[2][2048];     // [64 rows][32 k] swz, 4 KB/buf
    __shared__ __align__(16) short Wl[2][4096];     // 8 dim-frags x 512, 8 KB/buf

    const int rb = blockIdx.x >> 1, half = blockIdx.x & 1;
    const int rowbase = rb * 64;                    // Xbf row space
    const bool isQ = rowbase < 4096;
    if (!isQ) {
        const int gr = rowbase - 4096;
        if (((gr >> 6) & 3) >= nvb[gr >> 8]) return;   // beyond padding
    }

    const int tid = threadIdx.x;
    const int wave = tid >> 6, lane = tid & 63;
    const int l = lane & 15, g = lane >> 4;
    const int rw = (wave & 1) * 32;                 // row base in tile
    const int dn4 = (wave >> 1) * 4;                // dim-frag base
    const int dn = dn4 * 16;

    const int xrow = tid >> 2, xcl = tid & 3;       // X stage: 4 chunks/row
    const unsigned short* xsrc0 =
        Xbf + (size_t)(rowbase + xrow) * 768 + half * 384 + ((xcl ^ (xrow & 3)) * 8);

    auto stage = [&](int t, int p) {                // 3 gld_lds per wave
        // X: 1 instr/wave (tid-th 16B chunk), pre-swizzled source (T21)
        __builtin_amdgcn_global_load_lds(
            (const __attribute__((address_space(1))) void*)(xsrc0 + t * 32),
            (__attribute__((address_space(3))) void*)(&Xl[p][wave * 512]),
            16, 0, 0);
        // W: 2 instr/wave; step's 8 KB image block is contiguous
        const int kc32 = half * 12 + t;
        #pragma unroll
        for (int i = 0; i < 2; ++i) {
            const int j = wave * 2 + i;
            __builtin_amdgcn_global_load_lds(
                (const __attribute__((address_space(1))) void*)
                    (Wimg + ((size_t)kc32 * 8 + j) * 512 + lane * 8),
                (__attribute__((address_space(3))) void*)(&Wl[p][j * 512]),
                16, 0, 0);
        }
    };

    f32x4 acc[2][4];
    #pragma unroll
    for (int rt = 0; rt < 2; ++rt)
        #pragma unroll
        for (int n = 0; n < 4; ++n) acc[rt][n] = (f32x4)(0.0f);

    auto compute = [&](int p) {
        short8 af[2];
        #pragma unroll
        for (int rt = 0; rt < 2; ++rt) {
            const int row = rw + rt * 16 + l;
            const int c = g ^ (row & 3);            // swizzled read
            af[rt] = *reinterpret_cast<const short8*>(&Xl[p][row * 32 + c * 8]);
        }
        #pragma unroll
        for (int n = 0; n < 4; ++n) {
            short8 bf = *reinterpret_cast<const short8*>(&Wl[p][(dn4 + n) * 512 + lane * 8]);
            acc[0][n] = MFMA16(af[0], bf, acc[0][n]);
            acc[1][n] = MFMA16(af[1], bf, acc[1][n]);
        }
    };

    stage(0, 0);
    for (int t = 0; t < 12; ++t) {
        const int p = t & 1;
        if (t < 11) { stage(t + 1, p ^ 1); VMCNT(3); }
        else        { VMCNT(0); }
        RAW_BAR();                                  // tile t landed in all waves
        compute(p);
        RAW_BAR();                                  // buf p free before next stage
    }

    // fp32 partial store: acc[rt][n][r] = C[row=rw+rt*16+g*4+r][dim=dn+n*16+l]
    float* out = Pp + (size_t)half * 36864 * 128 + (size_t)rowbase * 128;
    #pragma unroll
    for (int rt = 0; rt < 2; ++rt)
        #pragma unroll
        for (int r = 0; r < 4; ++r) {
            const int row = rw + rt * 16 + g * 4 + r;
            #pragma unroll
            for (int n = 0; n < 4; ++n)
                out[row * 128 + dn + n * 16 + l] = acc[rt][n][r];
        }
}

// ---------------------------------------------------------------------------
// Kernel 1b: streaming combine + L2 norm. P[row] = l2norm(Pp0[row]+Pp1[row]),
// bf16, Q rows -> Qb, doc slots -> Db (already compacted). ~26 MB traffic.
// ---------------------------------------------------------------------------
__global__ __launch_bounds__(256) void combine_norm_kernel(
    const float* __restrict__ Pp, const int* __restrict__ nvb,
    unsigned short* __restrict__ Qb, unsigned short* __restrict__ Db)
{
    const int tid = threadIdx.x;
    const int row = blockIdx.x * 8 + (tid >> 5);     // 0..36863
    const int sub = tid & 31;
    const bool isQ = row < 4096;
    if (!isQ) {
        const int gr = row - 4096;
        if ((gr & 255) >= (nvb[gr >> 8] << 6)) return;
    }
    float4 a = reinterpret_cast<const float4*>(Pp + (size_t)row * 128)[sub];
    float4 b = reinterpret_cast<const float4*>(Pp + (size_t)(36864 + row) * 128)[sub];
    float4 s;
    s.x = a.x + b.x; s.y = a.y + b.y; s.z = a.z + b.z; s.w = a.w + b.w;
    float ss = s.x * s.x + s.y * s.y + s.z * s.z + s.w * s.w;
    ss += __shfl_xor(ss, 1);
    ss += __shfl_xor(ss, 2);
    ss += __shfl_xor(ss, 4);
    ss += __shfl_xor(ss, 8);
    ss += __shfl_xor(ss, 16);
    const float rn = rsqrtf(ss);
    short4v o;
    o[0] = f2bf(s.x * rn); o[1] = f2bf(s.y * rn);
    o[2] = f2bf(s.z * rn); o[3] = f2bf(s.w * rn);
    unsigned short* P = isQ ? Qb + (size_t)row * 128
                            : Db + (size_t)(row - 4096) * 128;
    *reinterpret_cast<short4v*>(P + sub * 4) = o;
}

// ---------------------------------------------------------------------------
// Kernel 2 (unchanged): out[b][c] = sum_q max_k Q[b,q,:] . Dc[c,k,:]
// Operand-swapped 32x32x16 (A=D tokens, B=Q): max over tokens is IN-LANE.
// ---------------------------------------------------------------------------
__global__ __launch_bounds__(512) void maxsim_kernel(
    const unsigned short* __restrict__ Qb, const unsigned short* __restrict__ Db,
    const int* __restrict__ nvb, float* __restrict__ out)
{
    __shared__ __align__(16) short Dlds[256][128];

    const int tid = threadIdx.x;
    const int wave = tid >> 6, lane = tid & 63;
    const int lo5 = lane & 31, hi = lane >> 5;
    const int c  = blockIdx.x & 127;
    const int bg = blockIdx.x >> 7;
    const int b  = bg * 8 + wave;

    const int npairs = nvb[c];                       // 1..4

    {
        const short8* src = reinterpret_cast<const short8*>(Db + (size_t)c * 256 * 128);
        #pragma unroll
        for (int i = 0; i < 8; ++i) {
            if (i * 32 >= npairs * 64) break;
            int idx = i * 512 + tid;
            int row = idx >> 4, ch = idx & 15;
            short8 v = src[row * 16 + (ch ^ (row & 15))];
            *reinterpret_cast<short8*>(&Dlds[row][ch * 8]) = v;
        }
    }
    __syncthreads();

    short8 a[8];
    const unsigned short* qp = Qb + ((size_t)b * 32 + lo5) * 128 + hi * 8;
    #pragma unroll
    for (int ks = 0; ks < 8; ++ks)
        a[ks] = *reinterpret_cast<const short8*>(qp + ks * 16);

    const int sw = lo5 & 15;
    float m = -1e30f;

    for (int p = 0; p < npairs; ++p) {
        f32x16 acc0 = (f32x16)(0.0f), acc1 = (f32x16)(0.0f);
        #pragma unroll
        for (int ks = 0; ks < 8; ++ks) {
            const int chs = ((2 * ks + hi) ^ sw) * 8;
            short8 d0 = *reinterpret_cast<const short8*>(&Dlds[p * 64 + lo5][chs]);
            short8 d1 = *reinterpret_cast<const short8*>(&Dlds[p * 64 + 32 + lo5][chs]);
            acc0 = MFMA32(d0, a[ks], acc0);
            acc1 = MFMA32(d1, a[ks], acc1);
        }
        #pragma unroll
        for (int r = 0; r < 16; ++r)
            m = fmaxf(m, fmaxf(acc0[r], acc1[r]));
    }

    m = fmaxf(m, __shfl_xor(m, 32));
    float s = m;
    s += __shfl_xor(s, 1);
    s += __shfl_xor(s, 2);
    s += __shfl_xor(s, 4);
    s += __shfl_xor(s, 8);
    s += __shfl_xor(s, 16);
    if (lane == 0) out[b * 128 + c] = s;
}

extern "C" void kernel_launch(void* const* d_in, const int* in_sizes, int n_in,
                              void* d_out, int out_size, void* d_ws, size_t ws_size,
                              hipStream_t stream)
{
    const float* qh    = (const float*)d_in[0];   // [128,32,768]
    const float* dh    = (const float*)d_in[1];   // [128,256,768]
    const float* W     = (const float*)d_in[2];   // [128,768]
    const int*   dmask = (const int*)d_in[3];     // [128,256]
    float* out = (float*)d_out;                   // [128,128]

    unsigned short* Qb   = (unsigned short*)d_ws;       // 4096x128 bf16 (1 MB)
    unsigned short* Db   = Qb + 4096 * 128;             // 32768x128 bf16 (8 MB)
    unsigned short* Wimg = Db + (size_t)32768 * 128;    // 196 KB
    unsigned short* Xbf  = Wimg + 12288 * 8;            // 36864x768 bf16 (56.6 MB)
    int* rowmap = (int*)(Xbf + (size_t)36864 * 768);    // 32768 ints
    int* nvb    = rowmap + 32768;                       // 128 ints
    float* Pp   = (float*)(nvb + 128);                  // 2 x 36864 x 128 fp32 (37.7 MB)

    hipLaunchKernelGGL(prep_kernel, dim3(176), dim3(256), 0, stream,
                       W, dmask, Wimg, rowmap, nvb);
    hipLaunchKernelGGL(cvt_kernel, dim3(4608), dim3(256), 0, stream,
                       qh, dh, rowmap, nvb, Xbf);
    // 576 row-blocks x 2 K-halves (adjacent pairs share X rows -> L2/L3 hits)
    hipLaunchKernelGGL(proj_half_kernel, dim3(1152), dim3(256), 0, stream,
                       Xbf, Wimg, nvb, Pp);
    hipLaunchKernelGGL(combine_norm_kernel, dim3(4608), dim3(256), 0, stream,
                       Pp, nvb, Qb, Db);
    hipLaunchKernelGGL(maxsim_kernel, dim3(2048), dim3(512), 0, stream,
                       Qb, Db, nvb, out);
}